// Round 5
// baseline (871.905 us; speedup 1.0000x reference)
//
#include <hip/hip_runtime.h>
#include <hip/hip_bf16.h>
#include <math.h>

typedef unsigned short u16;
typedef __bf16 bf16x8 __attribute__((ext_vector_type(8)));
typedef float f32x4 __attribute__((ext_vector_type(4)));

#define B_ 4
#define N_ 1024
#define DIM_ 256
#define HEADS_ 4
#define DH_ 64
#define MLP_ 1024
#define DEPTH_ 4

__device__ __forceinline__ float r2f(u16 r){ return __uint_as_float(((unsigned)r)<<16); }
__device__ __forceinline__ u16 f2r(float f){ __hip_bfloat16 h = __float2bfloat16(f); return *(u16*)&h; }
__device__ __forceinline__ float ldv(const float* p){ return *p; }
__device__ __forceinline__ float ldv(const u16* p){ return r2f(*p); }
__device__ __forceinline__ void stv(float* p, float v){ *p = v; }
__device__ __forceinline__ void stv(u16* p, float v){ *p = f2r(v); }

__device__ __forceinline__ float gelu_exact(float v){
  return 0.5f*v*(1.0f + erff(v*0.70710678118654752440f));
}

#define MFMA16(a,b,c) __builtin_amdgcn_mfma_f32_16x16x32_bf16(a,b,c,0,0,0)

// ---------------- copy ----------------
__global__ void copy_f32(const float* __restrict__ in, float* __restrict__ out, int n){
  int i = blockIdx.x*blockDim.x + threadIdx.x;
  if (i < n) out[i] = in[i];
}

// ---------------- fused: bsum = bf16(b0+b1) per head; G = softmax(mean_h(b0)*mean_h(b1)) ----------------
__global__ void prep_bias(const float* __restrict__ bias, u16* __restrict__ G, u16* __restrict__ bsum){
  int blk = blockIdx.x;           // b*N + i
  int i = blk & (N_-1);
  int b = blk >> 10;
  int t = threadIdx.x;
  __shared__ float sc[N_];
  __shared__ float red[256];
  long long base0 = ((long long)(b*HEADS_)*N_ + i)*(long long)N_;
  const long long hs = (long long)N_*N_;
  const long long cs = (long long)B_*HEADS_*N_*N_;
  float lmax = -3e38f;
  for (int jj=0;jj<4;jj++){
    int j = t + jj*256;
    float a = 0.f, s = 0.f;
    #pragma unroll
    for (int h=0;h<HEADS_;h++){
      float x0 = bias[base0 + h*hs + j];
      float x1 = bias[cs + base0 + h*hs + j];
      a += x0; s += x1;
      bsum[base0 + h*hs + j] = f2r(x0 + x1);
    }
    float v = (a*0.25f)*(s*0.25f);
    sc[j] = v;
    lmax = fmaxf(lmax, v);
  }
  red[t]=lmax; __syncthreads();
  for (int s=128;s>0;s>>=1){ if(t<s) red[t]=fmaxf(red[t],red[t+s]); __syncthreads(); }
  float m = red[0]; __syncthreads();
  float lsum = 0.f;
  for (int jj=0;jj<4;jj++){
    int j = t + jj*256;
    float e = __expf(sc[j]-m);
    sc[j]=e; lsum+=e;
  }
  red[t]=lsum; __syncthreads();
  for (int s=128;s>0;s>>=1){ if(t<s) red[t]+=red[t+s]; __syncthreads(); }
  float inv = 1.0f/red[0];
  u16* Grow = G + ((long long)b*N_ + i)*(long long)N_;
  for (int jj=0;jj<4;jj++){ int j=t+jj*256; Grow[j]=f2r(sc[j]*inv); }
}

// ---------------- LayerNorm (dim 256), fp32 math, bf16 out ----------------
template<typename TIN>
__global__ void ln_kernel(const TIN* __restrict__ X, u16* __restrict__ Y,
                          const float* __restrict__ g, const float* __restrict__ bvec, int relu){
  int row = blockIdx.x, t = threadIdx.x;
  __shared__ float red[256];
  float v = ldv(X + (long long)row*DIM_ + t);
  red[t]=v; __syncthreads();
  for (int s=128;s>0;s>>=1){ if(t<s) red[t]+=red[t+s]; __syncthreads(); }
  float mu = red[0]*(1.0f/DIM_); __syncthreads();
  float d = v - mu;
  red[t]=d*d; __syncthreads();
  for (int s=128;s>0;s>>=1){ if(t<s) red[t]+=red[t+s]; __syncthreads(); }
  float var = red[0]*(1.0f/DIM_);
  float y = d*rsqrtf(var+1e-5f)*g[t] + bvec[t];
  if (relu) y = fmaxf(y, 0.0f);
  Y[(long long)row*DIM_ + t] = f2r(y);
}

// ---------------- dual LayerNorm: blk<4096: Y1=LN(X1,g1,b1); else Y2=relu(LN(X2,g2,b2)) ----------------
__global__ void ln_dual(const float* __restrict__ X1, const u16* __restrict__ X2,
                        u16* __restrict__ Y1, u16* __restrict__ Y2,
                        const float* __restrict__ g1, const float* __restrict__ b1v,
                        const float* __restrict__ g2, const float* __restrict__ b2v){
  int blk = blockIdx.x, t = threadIdx.x;
  bool second = blk >= B_*N_;
  int row = second ? blk - B_*N_ : blk;
  __shared__ float red[256];
  float v = second ? r2f(X2[(long long)row*DIM_ + t]) : X1[(long long)row*DIM_ + t];
  red[t]=v; __syncthreads();
  for (int s=128;s>0;s>>=1){ if(t<s) red[t]+=red[t+s]; __syncthreads(); }
  float mu = red[0]*(1.0f/DIM_); __syncthreads();
  float d = v - mu;
  red[t]=d*d; __syncthreads();
  for (int s=128;s>0;s>>=1){ if(t<s) red[t]+=red[t+s]; __syncthreads(); }
  float var = red[0]*(1.0f/DIM_);
  float y;
  if (second){ y = fmaxf(d*rsqrtf(var+1e-5f)*g2[t] + b2v[t], 0.0f); Y2[(long long)row*DIM_+t]=f2r(y); }
  else       { y = d*rsqrtf(var+1e-5f)*g1[t] + b1v[t];              Y1[(long long)row*DIM_+t]=f2r(y); }
}

// ---------------- transpose + cast to bf16: out[c][r] = in[r][c] ----------------
template<typename TIN>
__global__ void tcast(const TIN* __restrict__ in, u16* __restrict__ out,
                      int ldin, int R, long long sIn, long long sOut){
  __shared__ float tile[32][33];
  int z = blockIdx.z;
  const TIN* I = in + (long long)z*sIn;
  u16* O = out + (long long)z*sOut;
  int c0 = blockIdx.x*32, r0 = blockIdx.y*32;
  int tx = threadIdx.x, ty = threadIdx.y;
  #pragma unroll
  for (int i=0;i<4;i++)
    tile[ty*4+i][tx] = ldv(I + (long long)(r0+ty*4+i)*ldin + c0+tx);
  __syncthreads();
  #pragma unroll
  for (int i=0;i<4;i++)
    O[(long long)(c0+ty*4+i)*R + r0+tx] = f2r(tile[tx][ty*4+i]);
}

// ---------------- wave GEMM: no LDS, direct global frags; wave = 32x32 out tile ----------------
// A [M,K] bf16 rm, BT [N,K] bf16 rm. grid (N/64, M/64, Z); 4 waves in 2x2.
template<typename OT, int ACT>
__global__ __launch_bounds__(256) void wgemm(
    const u16* __restrict__ A, const u16* __restrict__ BT, OT* __restrict__ Cb,
    int K, int lda, int ldbt, int ldc, int ZS,
    long long sAb, long long sAh, long long sBb, long long sBh,
    long long sCb, long long sCh,
    const float* __restrict__ colBias, const float* __restrict__ res)
{
  int z = blockIdx.z, zb = z>>ZS, zh = z & ((1<<ZS)-1);
  A  += zb*sAb + zh*sAh;
  BT += zb*sBb + zh*sBh;
  long long co = zb*sCb + zh*sCh;
  int tid = threadIdx.x, w = tid>>6, lane = tid&63;
  int lr = lane&15, qd = lane>>4;
  int m0 = blockIdx.y*64 + (w>>1)*32;
  int n0 = blockIdx.x*64 + (w&1)*32;
  const u16* Ap0 = A  + (long long)(m0+lr)*lda;
  const u16* Ap1 = A  + (long long)(m0+16+lr)*lda;
  const u16* Bp0 = BT + (long long)(n0+lr)*ldbt;
  const u16* Bp1 = BT + (long long)(n0+16+lr)*ldbt;
  f32x4 acc[2][2] = {};
  for (int k0=0; k0<K; k0+=64){
    #pragma unroll
    for (int ks=0; ks<2; ks++){
      int ko = k0 + ks*32 + qd*8;
      bf16x8 a0 = *(const bf16x8*)(Ap0+ko);
      bf16x8 a1 = *(const bf16x8*)(Ap1+ko);
      bf16x8 b0 = *(const bf16x8*)(Bp0+ko);
      bf16x8 b1 = *(const bf16x8*)(Bp1+ko);
      acc[0][0] = MFMA16(a0,b0,acc[0][0]);
      acc[0][1] = MFMA16(a0,b1,acc[0][1]);
      acc[1][0] = MFMA16(a1,b0,acc[1][0]);
      acc[1][1] = MFMA16(a1,b1,acc[1][1]);
    }
  }
  OT* C = Cb + co;
  const float* rs = res ? res + co : nullptr;
  #pragma unroll
  for (int rt=0;rt<2;rt++){
    #pragma unroll
    for (int ct=0;ct<2;ct++){
      int gc = n0 + ct*16 + lr;
      float cb = colBias ? colBias[gc] : 0.f;
      #pragma unroll
      for (int r=0;r<4;r++){
        int gr = m0 + rt*16 + qd*4 + r;
        float v = acc[rt][ct][r] + cb;
        if (ACT) v = gelu_exact(v);
        if (rs) v += rs[(long long)gr*ldc + gc];
        stv(C + (long long)gr*ldc + gc, v);
      }
    }
  }
}

static inline void gemm(hipStream_t st, const u16* A, const u16* BT, void* C, int outBf, int act,
    int M, int N, int K, int lda, int ldbt, int ldc, int Z, int ZS,
    long long sAb, long long sAh, long long sBb, long long sBh, long long sCb, long long sCh,
    const float* cb, const float* res)
{
  dim3 g(N/64, M/64, Z), b(256);
  if (outBf){
    if (act) wgemm<u16,1><<<g,b,0,st>>>(A,BT,(u16*)C,K,lda,ldbt,ldc,ZS,sAb,sAh,sBb,sBh,sCb,sCh,cb,res);
    else     wgemm<u16,0><<<g,b,0,st>>>(A,BT,(u16*)C,K,lda,ldbt,ldc,ZS,sAb,sAh,sBb,sBh,sCb,sCh,cb,res);
  } else {
    if (act) wgemm<float,1><<<g,b,0,st>>>(A,BT,(float*)C,K,lda,ldbt,ldc,ZS,sAb,sAh,sBb,sBh,sCb,sCh,cb,res);
    else     wgemm<float,0><<<g,b,0,st>>>(A,BT,(float*)C,K,lda,ldbt,ldc,ZS,sAb,sAh,sBb,sBh,sCb,sCh,cb,res);
  }
}

// ---------------- flash attention: per (b,h), 64 Q-rows per block, online softmax ----------------
// qb [4096,256], kvb [4096,512] (K cols 0..255, V cols 256..511), vt [B][256][1024] (V^T),
// bsum [B*H,N,N] bf16, out aob [4096,256] bf16.
__global__ __launch_bounds__(256) void flash_attn(
    const u16* __restrict__ qb, const u16* __restrict__ kvb,
    const u16* __restrict__ vt, const u16* __restrict__ bsum,
    u16* __restrict__ out)
{
  int z = blockIdx.z;          // b*4 + h
  int b = z>>2, h = z&3;
  int qt = blockIdx.x;         // Q tile (64 rows)
  int tid = threadIdx.x;
  int w = tid>>6, lane = tid&63;
  int lr = lane&15, qd = lane>>4;
  __shared__ u16 Pl[4][16][72];

  int qrow0 = qt*64 + w*16;
  const u16* qp = qb + ((long long)(b*N_) + qrow0 + lr)*DIM_ + h*DH_;
  bf16x8 aq0 = *(const bf16x8*)(qp + qd*8);
  bf16x8 aq1 = *(const bf16x8*)(qp + 32 + qd*8);

  f32x4 oacc[4] = {};
  float m_r[4] = {-3e38f,-3e38f,-3e38f,-3e38f};
  float l_r[4] = {0.f,0.f,0.f,0.f};

  const u16* kbase = kvb + ((long long)(b*N_))*512 + h*DH_;
  const u16* vbase = vt + (long long)b*(DIM_*N_) + (long long)(h*DH_)*N_;
  const u16* bias_base = bsum + ((long long)z*N_ + qrow0)*(long long)N_;

  for (int jt=0; jt<16; jt++){
    int j0 = jt*64;
    // scores: S[16 x 64] per wave
    f32x4 sacc[4] = {};
    #pragma unroll
    for (int nt=0; nt<4; nt++){
      const u16* kp = kbase + (long long)(j0 + nt*16 + lr)*512;
      bf16x8 bk0 = *(const bf16x8*)(kp + qd*8);
      bf16x8 bk1 = *(const bf16x8*)(kp + 32 + qd*8);
      sacc[nt] = MFMA16(aq0, bk0, sacc[nt]);
      sacc[nt] = MFMA16(aq1, bk1, sacc[nt]);
    }
    // bias + online softmax (row r = qd*4+r, col = nt*16+lr)
    #pragma unroll
    for (int r=0;r<4;r++){
      float pv[4];
      float vmax = -3e38f;
      #pragma unroll
      for (int nt=0;nt<4;nt++){
        float v = sacc[nt][r]*0.0625f
                + r2f(bias_base[(long long)(qd*4+r)*N_ + j0 + nt*16 + lr]);
        pv[nt] = v;
        vmax = fmaxf(vmax, v);
      }
      vmax = fmaxf(vmax, __shfl_xor(vmax,1));
      vmax = fmaxf(vmax, __shfl_xor(vmax,2));
      vmax = fmaxf(vmax, __shfl_xor(vmax,4));
      vmax = fmaxf(vmax, __shfl_xor(vmax,8));
      float newm = fmaxf(m_r[r], vmax);
      float alpha = __expf(m_r[r]-newm);
      m_r[r] = newm;
      float psum = 0.f;
      #pragma unroll
      for (int nt=0;nt<4;nt++){
        float p = __expf(pv[nt]-newm);
        psum += p;
        Pl[w][qd*4+r][nt*16+lr] = f2r(p);
      }
      psum += __shfl_xor(psum,1);
      psum += __shfl_xor(psum,2);
      psum += __shfl_xor(psum,4);
      psum += __shfl_xor(psum,8);
      l_r[r] = l_r[r]*alpha + psum;
      #pragma unroll
      for (int ot=0;ot<4;ot++) oacc[ot][r] *= alpha;
    }
    // P @ V   (P from wave-private LDS in A-layout; V frags direct from vt)
    #pragma unroll
    for (int ks=0;ks<2;ks++){
      bf16x8 ap = *(const bf16x8*)&Pl[w][lr][ks*32 + qd*8];
      #pragma unroll
      for (int ot=0;ot<4;ot++){
        const u16* vp = vbase + (long long)(ot*16+lr)*N_ + j0 + ks*32 + qd*8;
        bf16x8 bv = *(const bf16x8*)vp;
        oacc[ot] = MFMA16(ap, bv, oacc[ot]);
      }
    }
  }
  // epilogue: O /= l, store bf16
  #pragma unroll
  for (int r=0;r<4;r++){
    float inv = 1.0f/l_r[r];
    #pragma unroll
    for (int ot=0;ot<4;ot++){
      out[((long long)(b*N_) + qrow0 + qd*4 + r)*DIM_ + h*DH_ + ot*16 + lr]
          = f2r(oacc[ot][r]*inv);
    }
  }
}

// ---------------- host launch ----------------
extern "C" void kernel_launch(void* const* d_in, const int* in_sizes, int n_in,
                              void* d_out, int out_size, void* d_ws, size_t ws_size,
                              hipStream_t stream){
  const float* x_in   = (const float*)d_in[0];
  const float* abias  = (const float*)d_in[1];
  const float* ln1_g  = (const float*)d_in[2];
  const float* ln1_b  = (const float*)d_in[3];
  const float* Wkv    = (const float*)d_in[4];
  const float* Wq     = (const float*)d_in[5];
  const float* Wo     = (const float*)d_in[6];
  const float* bo     = (const float*)d_in[7];
  const float* ln2_g  = (const float*)d_in[8];
  const float* ln2_b  = (const float*)d_in[9];
  const float* W1     = (const float*)d_in[10];
  const float* b1     = (const float*)d_in[11];
  const float* W2     = (const float*)d_in[12];
  const float* b2     = (const float*)d_in[13];
  const float* Wg     = (const float*)d_in[14];
  const float* lng_g  = (const float*)d_in[15];
  const float* lng_b  = (const float*)d_in[16];

  char* ws = (char*)d_ws;
  float* xf   = (float*)(ws);                               // 4 MB fp32 residual
  u16*  Gb    = (u16*)(ws + (4ll<<20));                     // 8 MB
  u16*  bsum  = (u16*)(ws + (12ll<<20));                    // 32 MB
  u16*  kvb   = (u16*)(ws + (44ll<<20));                    // 4 MB
  u16*  vt    = (u16*)(ws + (48ll<<20));                    // 2 MB
  u16*  xT    = (u16*)(ws + (50ll<<20));                    // 2 MB
  u16*  tmp1b = (u16*)(ws + (52ll<<20));                    // 2 MB
  u16*  tmp2b = (u16*)(ws + (54ll<<20));                    // 2 MB
  u16*  xnb   = (u16*)(ws + (56ll<<20));                    // 2 MB
  u16*  xmab  = (u16*)(ws + (58ll<<20));                    // 2 MB
  u16*  qb    = (u16*)(ws + (60ll<<20));                    // 2 MB
  u16*  aob   = (u16*)(ws + (62ll<<20));                    // 2 MB
  u16*  h1b   = (u16*)(ws + (64ll<<20));                    // 8 MB
  u16*  WkvT  = (u16*)(ws + (72ll<<20));                    // 1 MB
  u16*  WqT   = (u16*)(ws + (73ll<<20));                    // 0.5 MB
  u16*  WoT   = (u16*)(ws + (73ll<<20) + (512ll<<10));      // 0.5 MB
  u16*  W1T   = (u16*)(ws + (74ll<<20));                    // 2 MB
  u16*  W2T   = (u16*)(ws + (76ll<<20));                    // 2 MB
  u16*  WgT   = (u16*)(ws + (78ll<<20));                    // 0.125 MB

  dim3 b256(256);
  dim3 tblk(32,8);
  int total = B_*N_*DIM_;

  // ---- preprocessing ----
  copy_f32<<<dim3((total+255)/256), b256, 0, stream>>>(x_in, xf, total);
  prep_bias<<<dim3(B_*N_), b256, 0, stream>>>(abias, Gb, bsum);
  tcast<float><<<dim3(16,8,DEPTH_),  tblk, 0, stream>>>(Wkv, WkvT, 512, 256, 131072, 131072);
  tcast<float><<<dim3(8,8,DEPTH_),   tblk, 0, stream>>>(Wq,  WqT,  256, 256, 65536, 65536);
  tcast<float><<<dim3(8,8,DEPTH_),   tblk, 0, stream>>>(Wo,  WoT,  256, 256, 65536, 65536);
  tcast<float><<<dim3(32,8,DEPTH_),  tblk, 0, stream>>>(W1,  W1T,  1024, 256, 262144, 262144);
  tcast<float><<<dim3(8,32,DEPTH_),  tblk, 0, stream>>>(W2,  W2T,  256, 1024, 262144, 262144);
  tcast<float><<<dim3(8,8,1),        tblk, 0, stream>>>(Wg,  WgT,  256, 256, 0, 0);

  for (int l=0; l<DEPTH_; l++){
    // xT[b] = bf16(x[b])^T
    tcast<float><<<dim3(8,32,B_), tblk, 0, stream>>>(xf, xT, 256, 1024, 262144, 262144);
    // tmp1 = G @ x   (z = batch)
    gemm(stream, Gb, xT, tmp1b, 1, 0, 1024, 256, 1024, 1024, 1024, 256, B_, 0,
         1048576,0, 262144,0, 262144,0, nullptr, nullptr);
    // tmp2 = tmp1 @ Wg
    gemm(stream, tmp1b, WgT, tmp2b, 1, 0, 4096, 256, 256, 256, 256, 256, 1, 0,
         0,0,0,0,0,0, nullptr, nullptr);
    // xn = LN(x, ln1) ; x_ma = relu(LN(tmp2, lng))
    ln_dual<<<dim3(2*B_*N_), b256, 0, stream>>>(xf, tmp2b, xnb, xmab,
        ln1_g + l*DIM_, ln1_b + l*DIM_, lng_g, lng_b);
    // kv = xn @ Wkv[l]
    gemm(stream, xnb, WkvT + (long long)l*131072, kvb, 1, 0, 4096, 512, 256, 256, 256, 512, 1, 0,
         0,0,0,0,0,0, nullptr, nullptr);
    // vt[b] = V^T
    tcast<u16><<<dim3(8,32,B_), tblk, 0, stream>>>(kvb + 256, vt, 512, 1024, 524288, 262144);
    // q = x_ma @ Wq[l]
    gemm(stream, xmab, WqT + (long long)l*65536, qb, 1, 0, 4096, 256, 256, 256, 256, 256, 1, 0,
         0,0,0,0,0,0, nullptr, nullptr);
    // ao = flash attention (scores+bias+softmax+PV fused)
    flash_attn<<<dim3(16,1,B_*HEADS_), b256, 0, stream>>>(qb, kvb, vt, bsum, aob);
    // x = x + ao @ Wo[l] + bo[l]
    gemm(stream, aob, WoT + (long long)l*65536, xf, 0, 0, 4096, 256, 256, 256, 256, 256, 1, 0,
         0,0,0,0,0,0, bo + l*DIM_, xf);
    // xn2 = LN(x, ln2)
    ln_kernel<float><<<dim3(B_*N_), b256, 0, stream>>>(xf, xnb, ln2_g + l*DIM_, ln2_b + l*DIM_, 0);
    // h1 = gelu(xn2 @ W1[l] + b1[l])
    gemm(stream, xnb, W1T + (long long)l*262144, h1b, 1, 1, 4096, 1024, 256, 256, 256, 1024, 1, 0,
         0,0,0,0,0,0, b1 + l*MLP_, nullptr);
    // x = x + h1 @ W2[l] + b2[l]  (last layer -> d_out)
    float* Cdst = (l == DEPTH_-1) ? (float*)d_out : xf;
    gemm(stream, h1b, W2T + (long long)l*262144, Cdst, 0, 0, 4096, 256, 1024, 1024, 1024, 256, 1, 0,
         0,0,0,0,0,0, b2 + l*DIM_, xf);
  }
}

// Round 6
// 846.554 us; speedup vs baseline: 1.0299x; 1.0299x over previous
//
#include <hip/hip_runtime.h>
#include <hip/hip_bf16.h>
#include <math.h>

typedef unsigned short u16;
typedef __bf16 bf16x8 __attribute__((ext_vector_type(8)));
typedef float f32x4 __attribute__((ext_vector_type(4)));

#define B_ 4
#define N_ 1024
#define DIM_ 256
#define HEADS_ 4
#define DH_ 64
#define MLP_ 1024
#define DEPTH_ 4

__device__ __forceinline__ float r2f(u16 r){ return __uint_as_float(((unsigned)r)<<16); }
__device__ __forceinline__ u16 f2r(float f){ __hip_bfloat16 h = __float2bfloat16(f); return *(u16*)&h; }
__device__ __forceinline__ void stv(float* p, float v){ *p = v; }
__device__ __forceinline__ void stv(u16* p, float v){ *p = f2r(v); }

__device__ __forceinline__ float gelu_exact(float v){
  return 0.5f*v*(1.0f + erff(v*0.70710678118654752440f));
}

#define MFMA16(a,b,c) __builtin_amdgcn_mfma_f32_16x16x32_bf16(a,b,c,0,0,0)

// ---------------- fused: bsum = bf16(b0+b1); G = softmax(mean_h(b0)*mean_h(b1)) ----------------
__global__ void prep_bias(const float* __restrict__ bias, u16* __restrict__ G, u16* __restrict__ bsum){
  int blk = blockIdx.x;           // b*N + i
  int i = blk & (N_-1);
  int b = blk >> 10;
  int t = threadIdx.x;
  __shared__ float sc[N_];
  __shared__ float red[256];
  long long base0 = ((long long)(b*HEADS_)*N_ + i)*(long long)N_;
  const long long hs = (long long)N_*N_;
  const long long cs = (long long)B_*HEADS_*N_*N_;
  float lmax = -3e38f;
  for (int jj=0;jj<4;jj++){
    int j = t + jj*256;
    float a = 0.f, s = 0.f;
    #pragma unroll
    for (int h=0;h<HEADS_;h++){
      float x0 = bias[base0 + h*hs + j];
      float x1 = bias[cs + base0 + h*hs + j];
      a += x0; s += x1;
      bsum[base0 + h*hs + j] = f2r(x0 + x1);
    }
    float v = (a*0.25f)*(s*0.25f);
    sc[j] = v;
    lmax = fmaxf(lmax, v);
  }
  red[t]=lmax; __syncthreads();
  for (int s=128;s>0;s>>=1){ if(t<s) red[t]=fmaxf(red[t],red[t+s]); __syncthreads(); }
  float m = red[0]; __syncthreads();
  float lsum = 0.f;
  for (int jj=0;jj<4;jj++){
    int j = t + jj*256;
    float e = __expf(sc[j]-m);
    sc[j]=e; lsum+=e;
  }
  red[t]=lsum; __syncthreads();
  for (int s=128;s>0;s>>=1){ if(t<s) red[t]+=red[t+s]; __syncthreads(); }
  float inv = 1.0f/red[0];
  u16* Grow = G + ((long long)b*N_ + i)*(long long)N_;
  for (int jj=0;jj<4;jj++){ int j=t+jj*256; Grow[j]=f2r(sc[j]*inv); }
}

// ---------------- LayerNorm (dim 256), fp32 in, bf16 out ----------------
__global__ void ln_kernel(const float* __restrict__ X, u16* __restrict__ Y,
                          const float* __restrict__ g, const float* __restrict__ bvec){
  int row = blockIdx.x, t = threadIdx.x;
  __shared__ float red[256];
  float v = X[(long long)row*DIM_ + t];
  red[t]=v; __syncthreads();
  for (int s=128;s>0;s>>=1){ if(t<s) red[t]+=red[t+s]; __syncthreads(); }
  float mu = red[0]*(1.0f/DIM_); __syncthreads();
  float d = v - mu;
  red[t]=d*d; __syncthreads();
  for (int s=128;s>0;s>>=1){ if(t<s) red[t]+=red[t+s]; __syncthreads(); }
  float var = red[0]*(1.0f/DIM_);
  Y[(long long)row*DIM_ + t] = f2r(d*rsqrtf(var+1e-5f)*g[t] + bvec[t]);
}

// ---------------- one-shot transpose+cast of all weights + x ----------------
__global__ void tcast_all(const float* __restrict__ Wkv, const float* __restrict__ Wq,
                          const float* __restrict__ Wo, const float* __restrict__ W1,
                          const float* __restrict__ W2, const float* __restrict__ Wg,
                          const float* __restrict__ xin,
                          u16* WkvT, u16* WqT, u16* WoT, u16* W1T, u16* W2T, u16* WgT, u16* xT){
  int z = blockIdx.z;
  const float* I; u16* O; int ldin, R, C;
  if (z < 4)       { I = Wkv + z*131072;      O = WkvT + z*131072;      ldin=512;  R=256;  C=512;  }
  else if (z < 8)  { I = Wq  + (z-4)*65536;   O = WqT  + (z-4)*65536;   ldin=256;  R=256;  C=256;  }
  else if (z < 12) { I = Wo  + (z-8)*65536;   O = WoT  + (z-8)*65536;   ldin=256;  R=256;  C=256;  }
  else if (z < 16) { I = W1  + (z-12)*262144; O = W1T  + (z-12)*262144; ldin=1024; R=256;  C=1024; }
  else if (z < 20) { I = W2  + (z-16)*262144; O = W2T  + (z-16)*262144; ldin=256;  R=1024; C=256;  }
  else if (z == 20){ I = Wg;                  O = WgT;                  ldin=256;  R=256;  C=256;  }
  else             { I = xin + (z-21)*262144; O = xT   + (z-21)*262144; ldin=256;  R=1024; C=256;  }
  int c0 = blockIdx.x*32, r0 = blockIdx.y*32;
  if (c0 >= C || r0 >= R) return;
  __shared__ float tile[32][33];
  int tx = threadIdx.x, ty = threadIdx.y;
  #pragma unroll
  for (int i=0;i<4;i++)
    tile[ty*4+i][tx] = I[(long long)(r0+ty*4+i)*ldin + c0+tx];
  __syncthreads();
  #pragma unroll
  for (int i=0;i<4;i++)
    O[(long long)(c0+ty*4+i)*R + r0+tx] = f2r(tile[tx][ty*4+i]);
}

// ---------------- wave GEMM (64x64 block tile, no LDS): C = [res+] act(A@BT^T + colBias) ------
// optional vt: for kv-gemm, cols>=256 (V) also written transposed to vt[b][c][r].
template<typename OT, int ACT>
__global__ __launch_bounds__(256) void wgemm(
    const u16* __restrict__ A, const u16* __restrict__ BT, OT* __restrict__ Cb,
    int K, int lda, int ldbt, int ldc, int ZS,
    long long sAb, long long sAh, long long sBb, long long sBh,
    long long sCb, long long sCh,
    const float* __restrict__ colBias, const float* __restrict__ res,
    u16* __restrict__ vt)
{
  int z = blockIdx.z, zb = z>>ZS, zh = z & ((1<<ZS)-1);
  A  += zb*sAb + zh*sAh;
  BT += zb*sBb + zh*sBh;
  long long co = zb*sCb + zh*sCh;
  int tid = threadIdx.x, w = tid>>6, lane = tid&63;
  int lr = lane&15, qd = lane>>4;
  int m0 = blockIdx.y*64 + (w>>1)*32;
  int n0 = blockIdx.x*64 + (w&1)*32;
  const u16* Ap0 = A  + (long long)(m0+lr)*lda;
  const u16* Ap1 = A  + (long long)(m0+16+lr)*lda;
  const u16* Bp0 = BT + (long long)(n0+lr)*ldbt;
  const u16* Bp1 = BT + (long long)(n0+16+lr)*ldbt;
  f32x4 acc[2][2] = {};
  for (int k0=0; k0<K; k0+=64){
    #pragma unroll
    for (int ks=0; ks<2; ks++){
      int ko = k0 + ks*32 + qd*8;
      bf16x8 a0 = *(const bf16x8*)(Ap0+ko);
      bf16x8 a1 = *(const bf16x8*)(Ap1+ko);
      bf16x8 b0 = *(const bf16x8*)(Bp0+ko);
      bf16x8 b1 = *(const bf16x8*)(Bp1+ko);
      acc[0][0] = MFMA16(a0,b0,acc[0][0]);
      acc[0][1] = MFMA16(a0,b1,acc[0][1]);
      acc[1][0] = MFMA16(a1,b0,acc[1][0]);
      acc[1][1] = MFMA16(a1,b1,acc[1][1]);
    }
  }
  OT* C = Cb + co;
  const float* rs = res ? res + co : nullptr;
  #pragma unroll
  for (int rt=0;rt<2;rt++){
    #pragma unroll
    for (int ct=0;ct<2;ct++){
      int gc = n0 + ct*16 + lr;
      float cb = colBias ? colBias[gc] : 0.f;
      #pragma unroll
      for (int r=0;r<4;r++){
        int gr = m0 + rt*16 + qd*4 + r;
        float v = acc[rt][ct][r] + cb;
        if (ACT) v = gelu_exact(v);
        if (rs) v += rs[(long long)gr*ldc + gc];
        stv(C + (long long)gr*ldc + gc, v);
        if (vt && gc >= 256){
          int b = gr>>10, rl = gr&1023;
          vt[(long long)b*262144 + (long long)(gc-256)*1024 + rl] = f2r(v);
        }
      }
    }
  }
}

static inline void gemm(hipStream_t st, const u16* A, const u16* BT, void* C, int outBf, int act,
    int M, int N, int K, int lda, int ldbt, int ldc, int Z, int ZS,
    long long sAb, long long sAh, long long sBb, long long sBh, long long sCb, long long sCh,
    const float* cb, const float* res, u16* vt)
{
  dim3 g(N/64, M/64, Z), b(256);
  if (outBf){
    if (act) wgemm<u16,1><<<g,b,0,st>>>(A,BT,(u16*)C,K,lda,ldbt,ldc,ZS,sAb,sAh,sBb,sBh,sCb,sCh,cb,res,vt);
    else     wgemm<u16,0><<<g,b,0,st>>>(A,BT,(u16*)C,K,lda,ldbt,ldc,ZS,sAb,sAh,sBb,sBh,sCb,sCh,cb,res,vt);
  } else {
    if (act) wgemm<float,1><<<g,b,0,st>>>(A,BT,(float*)C,K,lda,ldbt,ldc,ZS,sAb,sAh,sBb,sBh,sCb,sCh,cb,res,vt);
    else     wgemm<float,0><<<g,b,0,st>>>(A,BT,(float*)C,K,lda,ldbt,ldc,ZS,sAb,sAh,sBb,sBh,sCb,sCh,cb,res,vt);
  }
}

// ---------------- fused GEMM (N=256 wide, 1 wave / 16 rows) + epilogue LN variants ----------------
// MODE 0: lnOut = relu(LN(acc))                            (Wg -> x_ma)
// MODE 1: v = acc+colBias+res; fout=v; lnOut = LN(v)       (Wo -> xf, xn2)
// MODE 2: v = acc+colBias+res; fout=v; [xTout=v^T bf16]; [lnOut=LN(v)]   (W2 -> xf/d_out, xT, xn1')
template<int MODE>
__global__ __launch_bounds__(64) void gemmln(
    const u16* __restrict__ A, const u16* __restrict__ BT, int K, int ldbt,
    const float* __restrict__ colBias, const float* __restrict__ res,
    float* __restrict__ fout,
    const float* __restrict__ lng, const float* __restrict__ lnb,
    u16* __restrict__ lnOut, u16* __restrict__ xTout)
{
  int lane = threadIdx.x;
  int lr = lane&15, qd = lane>>4;
  int m0 = blockIdx.x*16;
  const u16* Ap = A + (long long)(m0+lr)*K;
  f32x4 acc[16] = {};
  for (int k0=0;k0<K;k0+=32){
    bf16x8 af = *(const bf16x8*)(Ap + k0 + qd*8);
    #pragma unroll
    for (int ct=0;ct<16;ct++){
      bf16x8 bfv = *(const bf16x8*)(BT + (long long)(ct*16+lr)*ldbt + k0 + qd*8);
      acc[ct] = MFMA16(af, bfv, acc[ct]);
    }
  }
  #pragma unroll
  for (int r=0;r<4;r++){
    int row = m0 + qd*4 + r;
    float v[16];
    #pragma unroll
    for (int ct=0;ct<16;ct++){
      float x = acc[ct][r];
      if (MODE>=1){ int col = ct*16+lr; x += colBias[col] + res[(long long)row*DIM_ + col]; }
      v[ct] = x;
    }
    if (MODE>=1){
      #pragma unroll
      for (int ct=0;ct<16;ct++) fout[(long long)row*DIM_ + ct*16+lr] = v[ct];
    }
    if (MODE==2 && xTout){
      int b = row>>10, rl = row&1023;
      #pragma unroll
      for (int ct=0;ct<16;ct++)
        xTout[(long long)b*262144 + (long long)(ct*16+lr)*1024 + rl] = f2r(v[ct]);
    }
    if (MODE==0 || lnOut){
      float s=0.f;
      #pragma unroll
      for (int ct=0;ct<16;ct++) s += v[ct];
      s += __shfl_xor(s,1); s += __shfl_xor(s,2); s += __shfl_xor(s,4); s += __shfl_xor(s,8);
      float mu = s*(1.0f/256.0f);
      float s2=0.f;
      #pragma unroll
      for (int ct=0;ct<16;ct++){ float d=v[ct]-mu; s2 += d*d; }
      s2 += __shfl_xor(s2,1); s2 += __shfl_xor(s2,2); s2 += __shfl_xor(s2,4); s2 += __shfl_xor(s2,8);
      float rstd = rsqrtf(s2*(1.0f/256.0f)+1e-5f);
      #pragma unroll
      for (int ct=0;ct<16;ct++){
        int col = ct*16+lr;
        float y = (v[ct]-mu)*rstd*lng[col] + lnb[col];
        if (MODE==0) y = fmaxf(y,0.f);
        lnOut[(long long)row*DIM_ + col] = f2r(y);
      }
    }
  }
}

// ---------------- flash attention (bias staged via wave-private LDS) ----------------
__global__ __launch_bounds__(256) void flash_attn(
    const u16* __restrict__ qb, const u16* __restrict__ kvb,
    const u16* __restrict__ vt, const u16* __restrict__ bsum,
    u16* __restrict__ out)
{
  int z = blockIdx.z;          // b*4 + h
  int b = z>>2, h = z&3;
  int qt = blockIdx.x;
  int tid = threadIdx.x;
  int w = tid>>6, lane = tid&63;
  int lr = lane&15, qd = lane>>4;
  __shared__ u16 Pl[4][16][72];
  __shared__ u16 sb[4][16][72];

  int qrow0 = qt*64 + w*16;
  const u16* qp = qb + ((long long)(b*N_) + qrow0 + lr)*DIM_ + h*DH_;
  bf16x8 aq0 = *(const bf16x8*)(qp + qd*8);
  bf16x8 aq1 = *(const bf16x8*)(qp + 32 + qd*8);

  f32x4 oacc[4] = {};
  float m_r[4] = {-3e38f,-3e38f,-3e38f,-3e38f};
  float l_r[4] = {0.f,0.f,0.f,0.f};

  const u16* kbase = kvb + ((long long)(b*N_))*512 + h*DH_;
  const u16* vbase = vt + (long long)b*(DIM_*N_) + (long long)(h*DH_)*N_;
  const u16* bias_base = bsum + ((long long)z*N_ + qrow0)*(long long)N_;
  int srr = lane>>2, scc = (lane&3)*16;

  for (int jt=0; jt<16; jt++){
    int j0 = jt*64;
    // stage this wave's 16x64 bias subtile, coalesced (32 B/lane)
    {
      const u16* gs = bias_base + (long long)srr*N_ + j0 + scc;
      uint4 t0 = *(const uint4*)gs;
      uint4 t1 = *(const uint4*)(gs+8);
      *(uint4*)&sb[w][srr][scc]   = t0;
      *(uint4*)&sb[w][srr][scc+8] = t1;
    }
    // scores: S[16 x 64] per wave
    f32x4 sacc[4] = {};
    #pragma unroll
    for (int nt=0; nt<4; nt++){
      const u16* kp = kbase + (long long)(j0 + nt*16 + lr)*512;
      bf16x8 bk0 = *(const bf16x8*)(kp + qd*8);
      bf16x8 bk1 = *(const bf16x8*)(kp + 32 + qd*8);
      sacc[nt] = MFMA16(aq0, bk0, sacc[nt]);
      sacc[nt] = MFMA16(aq1, bk1, sacc[nt]);
    }
    // bias + online softmax (row r = qd*4+r, col = nt*16+lr)
    #pragma unroll
    for (int r=0;r<4;r++){
      float pv[4];
      float vmax = -3e38f;
      #pragma unroll
      for (int nt=0;nt<4;nt++){
        float v = sacc[nt][r]*0.0625f + r2f(sb[w][qd*4+r][nt*16+lr]);
        pv[nt] = v;
        vmax = fmaxf(vmax, v);
      }
      vmax = fmaxf(vmax, __shfl_xor(vmax,1));
      vmax = fmaxf(vmax, __shfl_xor(vmax,2));
      vmax = fmaxf(vmax, __shfl_xor(vmax,4));
      vmax = fmaxf(vmax, __shfl_xor(vmax,8));
      float newm = fmaxf(m_r[r], vmax);
      float alpha = __expf(m_r[r]-newm);
      m_r[r] = newm;
      float psum = 0.f;
      #pragma unroll
      for (int nt=0;nt<4;nt++){
        float p = __expf(pv[nt]-newm);
        psum += p;
        Pl[w][qd*4+r][nt*16+lr] = f2r(p);
      }
      psum += __shfl_xor(psum,1);
      psum += __shfl_xor(psum,2);
      psum += __shfl_xor(psum,4);
      psum += __shfl_xor(psum,8);
      l_r[r] = l_r[r]*alpha + psum;
      #pragma unroll
      for (int ot=0;ot<4;ot++) oacc[ot][r] *= alpha;
    }
    // P @ V
    #pragma unroll
    for (int ks=0;ks<2;ks++){
      bf16x8 ap = *(const bf16x8*)&Pl[w][lr][ks*32 + qd*8];
      #pragma unroll
      for (int ot=0;ot<4;ot++){
        const u16* vp = vbase + (long long)(ot*16+lr)*N_ + j0 + ks*32 + qd*8;
        bf16x8 bv = *(const bf16x8*)vp;
        oacc[ot] = MFMA16(ap, bv, oacc[ot]);
      }
    }
  }
  #pragma unroll
  for (int r=0;r<4;r++){
    float inv = 1.0f/l_r[r];
    #pragma unroll
    for (int ot=0;ot<4;ot++){
      out[((long long)(b*N_) + qrow0 + qd*4 + r)*DIM_ + h*DH_ + ot*16 + lr]
          = f2r(oacc[ot][r]*inv);
    }
  }
}

// ---------------- host launch ----------------
extern "C" void kernel_launch(void* const* d_in, const int* in_sizes, int n_in,
                              void* d_out, int out_size, void* d_ws, size_t ws_size,
                              hipStream_t stream){
  const float* x_in   = (const float*)d_in[0];
  const float* abias  = (const float*)d_in[1];
  const float* ln1_g  = (const float*)d_in[2];
  const float* ln1_b  = (const float*)d_in[3];
  const float* Wkv    = (const float*)d_in[4];
  const float* Wq     = (const float*)d_in[5];
  const float* Wo     = (const float*)d_in[6];
  const float* bo     = (const float*)d_in[7];
  const float* ln2_g  = (const float*)d_in[8];
  const float* ln2_b  = (const float*)d_in[9];
  const float* W1     = (const float*)d_in[10];
  const float* b1     = (const float*)d_in[11];
  const float* W2     = (const float*)d_in[12];
  const float* b2     = (const float*)d_in[13];
  const float* Wg     = (const float*)d_in[14];
  const float* lng_g  = (const float*)d_in[15];
  const float* lng_b  = (const float*)d_in[16];

  char* ws = (char*)d_ws;
  float* xf   = (float*)(ws);                               // 4 MB fp32 residual
  u16*  Gb    = (u16*)(ws + (4ll<<20));                     // 8 MB
  u16*  bsum  = (u16*)(ws + (12ll<<20));                    // 32 MB
  u16*  kvb   = (u16*)(ws + (44ll<<20));                    // 4 MB
  u16*  vt    = (u16*)(ws + (48ll<<20));                    // 2 MB
  u16*  xT    = (u16*)(ws + (50ll<<20));                    // 2 MB
  u16*  tmp1b = (u16*)(ws + (52ll<<20));                    // 2 MB
  u16*  xnb   = (u16*)(ws + (54ll<<20));                    // 2 MB (LN1 / LN2 staging)
  u16*  xmab  = (u16*)(ws + (56ll<<20));                    // 2 MB
  u16*  qb    = (u16*)(ws + (58ll<<20));                    // 2 MB
  u16*  aob   = (u16*)(ws + (60ll<<20));                    // 2 MB
  u16*  h1b   = (u16*)(ws + (62ll<<20));                    // 8 MB
  u16*  WkvT  = (u16*)(ws + (70ll<<20));                    // 1 MB
  u16*  WqT   = (u16*)(ws + (71ll<<20));                    // 0.5 MB
  u16*  WoT   = (u16*)(ws + (71ll<<20) + (512ll<<10));      // 0.5 MB
  u16*  W1T   = (u16*)(ws + (72ll<<20));                    // 2 MB
  u16*  W2T   = (u16*)(ws + (74ll<<20));                    // 2 MB
  u16*  WgT   = (u16*)(ws + (76ll<<20));                    // 0.125 MB

  dim3 b256(256);

  // ---- prep: 3 dispatches ----
  prep_bias<<<dim3(B_*N_), b256, 0, stream>>>(abias, Gb, bsum);
  tcast_all<<<dim3(32,32,25), dim3(32,8), 0, stream>>>(Wkv,Wq,Wo,W1,W2,Wg,x_in,
                                                       WkvT,WqT,WoT,W1T,W2T,WgT,xT);
  ln_kernel<<<dim3(B_*N_), b256, 0, stream>>>(x_in, xnb, ln1_g, ln1_b);

  for (int l=0; l<DEPTH_; l++){
    const float* resx = (l==0) ? x_in : xf;
    // tmp1 = G @ x (z=batch)
    gemm(stream, Gb, xT, tmp1b, 1, 0, 1024, 256, 1024, 1024, 1024, 256, B_, 0,
         1048576,0, 262144,0, 262144,0, nullptr, nullptr, nullptr);
    // x_ma = relu(LN(tmp1 @ Wg))
    gemmln<0><<<dim3(256), dim3(64), 0, stream>>>(tmp1b, WgT, 256, 256,
        nullptr, nullptr, nullptr, lng_g, lng_b, xmab, nullptr);
    // kv = xn @ Wkv[l]; V also written transposed to vt
    gemm(stream, xnb, WkvT + (long long)l*131072, kvb, 1, 0, 4096, 512, 256, 256, 256, 512, 1, 0,
         0,0,0,0,0,0, nullptr, nullptr, vt);
    // q = x_ma @ Wq[l]
    gemm(stream, xmab, WqT + (long long)l*65536, qb, 1, 0, 4096, 256, 256, 256, 256, 256, 1, 0,
         0,0,0,0,0,0, nullptr, nullptr, nullptr);
    // ao = flash attention
    flash_attn<<<dim3(16,1,B_*HEADS_), b256, 0, stream>>>(qb, kvb, vt, bsum, aob);
    // x = x + ao@Wo + bo ; xn2 = LN2(x)
    gemmln<1><<<dim3(256), dim3(64), 0, stream>>>(aob, WoT + (long long)l*65536, 256, 256,
        bo + l*DIM_, resx, xf, ln2_g + l*DIM_, ln2_b + l*DIM_, xnb, nullptr);
    // h1 = gelu(xn2 @ W1 + b1)
    gemm(stream, xnb, W1T + (long long)l*262144, h1b, 1, 1, 4096, 1024, 256, 256, 256, 1024, 1, 0,
         0,0,0,0,0,0, b1 + l*MLP_, nullptr, nullptr);
    // x = x + h1@W2 + b2 ; (l<3: also xT = x^T bf16, xn = LN1[l+1](x)) ; l=3 -> d_out
    if (l < DEPTH_-1){
      gemmln<2><<<dim3(256), dim3(64), 0, stream>>>(h1b, W2T + (long long)l*262144, 1024, 1024,
          b2 + l*DIM_, xf, xf, ln1_g + (l+1)*DIM_, ln1_b + (l+1)*DIM_, xnb, xT);
    } else {
      gemmln<2><<<dim3(256), dim3(64), 0, stream>>>(h1b, W2T + (long long)l*262144, 1024, 1024,
          b2 + l*DIM_, xf, (float*)d_out, nullptr, nullptr, nullptr, nullptr);
    }
  }
}

// Round 7
// 730.991 us; speedup vs baseline: 1.1928x; 1.1581x over previous
//
#include <hip/hip_runtime.h>
#include <hip/hip_bf16.h>
#include <math.h>

typedef unsigned short u16;
typedef __bf16 bf16x8 __attribute__((ext_vector_type(8)));
typedef float f32x4 __attribute__((ext_vector_type(4)));

#define B_ 4
#define N_ 1024
#define DIM_ 256
#define HEADS_ 4
#define DH_ 64
#define MLP_ 1024
#define DEPTH_ 4

__device__ __forceinline__ float r2f(u16 r){ return __uint_as_float(((unsigned)r)<<16); }
__device__ __forceinline__ u16 f2r(float f){ __hip_bfloat16 h = __float2bfloat16(f); return *(u16*)&h; }

__device__ __forceinline__ float gelu_exact(float v){
  return 0.5f*v*(1.0f + erff(v*0.70710678118654752440f));
}

#define MFMA16(a,b,c) __builtin_amdgcn_mfma_f32_16x16x32_bf16(a,b,c,0,0,0)

// ---------------- fused: bsum = bf16(b0+b1); G = softmax(mean_h(b0)*mean_h(b1)) ----------------
__global__ void prep_bias(const float* __restrict__ bias, u16* __restrict__ G, u16* __restrict__ bsum){
  int blk = blockIdx.x;           // b*N + i
  int i = blk & (N_-1);
  int b = blk >> 10;
  int t = threadIdx.x;
  __shared__ float sc[N_];
  __shared__ float red[256];
  long long base0 = ((long long)(b*HEADS_)*N_ + i)*(long long)N_;
  const long long hs = (long long)N_*N_;
  const long long cs = (long long)B_*HEADS_*N_*N_;
  float lmax = -3e38f;
  for (int jj=0;jj<4;jj++){
    int j = t + jj*256;
    float a = 0.f, s = 0.f;
    #pragma unroll
    for (int h=0;h<HEADS_;h++){
      float x0 = bias[base0 + h*hs + j];
      float x1 = bias[cs + base0 + h*hs + j];
      a += x0; s += x1;
      bsum[base0 + h*hs + j] = f2r(x0 + x1);
    }
    float v = (a*0.25f)*(s*0.25f);
    sc[j] = v;
    lmax = fmaxf(lmax, v);
  }
  red[t]=lmax; __syncthreads();
  for (int s=128;s>0;s>>=1){ if(t<s) red[t]=fmaxf(red[t],red[t+s]); __syncthreads(); }
  float m = red[0]; __syncthreads();
  float lsum = 0.f;
  for (int jj=0;jj<4;jj++){
    int j = t + jj*256;
    float e = __expf(sc[j]-m);
    sc[j]=e; lsum+=e;
  }
  red[t]=lsum; __syncthreads();
  for (int s=128;s>0;s>>=1){ if(t<s) red[t]+=red[t+s]; __syncthreads(); }
  float inv = 1.0f/red[0];
  u16* Grow = G + ((long long)b*N_ + i)*(long long)N_;
  for (int jj=0;jj<4;jj++){ int j=t+jj*256; Grow[j]=f2r(sc[j]*inv); }
}

// ---------------- LayerNorm (dim 256), fp32 in, bf16 out ----------------
__global__ void ln_kernel(const float* __restrict__ X, u16* __restrict__ Y,
                          const float* __restrict__ g, const float* __restrict__ bvec){
  int row = blockIdx.x, t = threadIdx.x;
  __shared__ float red[256];
  float v = X[(long long)row*DIM_ + t];
  red[t]=v; __syncthreads();
  for (int s=128;s>0;s>>=1){ if(t<s) red[t]+=red[t+s]; __syncthreads(); }
  float mu = red[0]*(1.0f/DIM_); __syncthreads();
  float d = v - mu;
  red[t]=d*d; __syncthreads();
  for (int s=128;s>0;s>>=1){ if(t<s) red[t]+=red[t+s]; __syncthreads(); }
  float var = red[0]*(1.0f/DIM_);
  Y[(long long)row*DIM_ + t] = f2r(d*rsqrtf(var+1e-5f)*g[t] + bvec[t]);
}

// ---------------- one-shot transpose+cast of all weights + x ----------------
__global__ void tcast_all(const float* __restrict__ Wkv, const float* __restrict__ Wq,
                          const float* __restrict__ Wo, const float* __restrict__ W1,
                          const float* __restrict__ W2, const float* __restrict__ Wg,
                          const float* __restrict__ xin,
                          u16* WkvT, u16* WqT, u16* WoT, u16* W1T, u16* W2T, u16* WgT, u16* xT){
  int z = blockIdx.z;
  const float* I; u16* O; int ldin, R, C;
  if (z < 4)       { I = Wkv + z*131072;      O = WkvT + z*131072;      ldin=512;  R=256;  C=512;  }
  else if (z < 8)  { I = Wq  + (z-4)*65536;   O = WqT  + (z-4)*65536;   ldin=256;  R=256;  C=256;  }
  else if (z < 12) { I = Wo  + (z-8)*65536;   O = WoT  + (z-8)*65536;   ldin=256;  R=256;  C=256;  }
  else if (z < 16) { I = W1  + (z-12)*262144; O = W1T  + (z-12)*262144; ldin=1024; R=256;  C=1024; }
  else if (z < 20) { I = W2  + (z-16)*262144; O = W2T  + (z-16)*262144; ldin=256;  R=1024; C=256;  }
  else if (z == 20){ I = Wg;                  O = WgT;                  ldin=256;  R=256;  C=256;  }
  else             { I = xin + (z-21)*262144; O = xT   + (z-21)*262144; ldin=256;  R=1024; C=256;  }
  int c0 = blockIdx.x*32, r0 = blockIdx.y*32;
  if (c0 >= C || r0 >= R) return;
  __shared__ float tile[32][33];
  int tx = threadIdx.x, ty = threadIdx.y;
  #pragma unroll
  for (int i=0;i<4;i++)
    tile[ty*4+i][tx] = I[(long long)(r0+ty*4+i)*ldin + c0+tx];
  __syncthreads();
  #pragma unroll
  for (int i=0;i<4;i++)
    O[(long long)(c0+ty*4+i)*R + r0+tx] = f2r(tile[tx][ty*4+i]);
}

// ================= layer_pre: Gx -> Wg -> LN/relu -> Wq = q ; xn @ Wkv = kv (+vt) =================
// grid 256 blocks x 512 thr (8 waves). Block owns 16 rows.
__global__ __launch_bounds__(512) void layer_pre(
    const u16* __restrict__ Gb, const u16* __restrict__ xT, const u16* __restrict__ xnb,
    const u16* __restrict__ WgT, const u16* __restrict__ WqT, const u16* __restrict__ WkvT,
    const float* __restrict__ lng, const float* __restrict__ lnb,
    u16* __restrict__ qb, u16* __restrict__ kvb, u16* __restrict__ vt)
{
  __shared__ float Gx_s[16][264];
  __shared__ float t2_s[16][264];
  __shared__ u16  xma_s[16][264];
  int tid = threadIdx.x;
  int w = tid>>6, lane = tid&63, lr = lane&15, qd = lane>>4;
  int row0 = blockIdx.x*16;
  int batch = row0>>10, brow0 = row0&1023;

  // ---- stage1: Gx = G[rows] @ x  (kw: K-half, cw: 64-col group)
  {
    int kw = w>>2, cw = w&3;
    const u16* Ap = Gb + (long long)batch*1048576 + (long long)(brow0+lr)*1024 + kw*512;
    const u16* Bp = xT + (long long)batch*262144 + (long long)kw*512;
    f32x4 acc[4] = {};
    for (int k0=0;k0<512;k0+=32){
      bf16x8 af = *(const bf16x8*)(Ap + k0 + qd*8);
      #pragma unroll
      for (int nt=0;nt<4;nt++){
        bf16x8 bf = *(const bf16x8*)(Bp + (long long)(cw*64+nt*16+lr)*1024 + k0 + qd*8);
        acc[nt] = MFMA16(af,bf,acc[nt]);
      }
    }
    if (kw==0){
      #pragma unroll
      for (int nt=0;nt<4;nt++)
        #pragma unroll
        for (int r=0;r<4;r++) Gx_s[qd*4+r][cw*64+nt*16+lr] = acc[nt][r];
    }
    __syncthreads();
    if (kw==1){
      #pragma unroll
      for (int nt=0;nt<4;nt++)
        #pragma unroll
        for (int r=0;r<4;r++) Gx_s[qd*4+r][cw*64+nt*16+lr] += acc[nt][r];
    }
    __syncthreads();
  }
  // ---- stage2: t2 = Gx @ Wg  (each wave 2 col-tiles)
  {
    f32x4 acc[2] = {};
    for (int k0=0;k0<256;k0+=32){
      bf16x8 af;
      #pragma unroll
      for (int i=0;i<8;i++) af[i] = (__bf16)Gx_s[lr][k0+qd*8+i];
      #pragma unroll
      for (int i=0;i<2;i++){
        bf16x8 bf = *(const bf16x8*)(WgT + (long long)((w*2+i)*16+lr)*256 + k0 + qd*8);
        acc[i] = MFMA16(af,bf,acc[i]);
      }
    }
    #pragma unroll
    for (int i=0;i<2;i++)
      #pragma unroll
      for (int r=0;r<4;r++) t2_s[qd*4+r][(w*2+i)*16+lr] = acc[i][r];
  }
  __syncthreads();
  // ---- LN(t2)+relu -> xma_s
  {
    int r = tid>>5, cg = tid&31;
    float v[8]; float s=0.f;
    #pragma unroll
    for (int i=0;i<8;i++){ v[i] = t2_s[r][cg*8+i]; s += v[i]; }
    s += __shfl_xor(s,1); s += __shfl_xor(s,2); s += __shfl_xor(s,4); s += __shfl_xor(s,8); s += __shfl_xor(s,16);
    float mu = s*(1.0f/256.0f);
    float s2=0.f;
    #pragma unroll
    for (int i=0;i<8;i++){ float d=v[i]-mu; s2 += d*d; }
    s2 += __shfl_xor(s2,1); s2 += __shfl_xor(s2,2); s2 += __shfl_xor(s2,4); s2 += __shfl_xor(s2,8); s2 += __shfl_xor(s2,16);
    float rstd = rsqrtf(s2*(1.0f/256.0f)+1e-5f);
    #pragma unroll
    for (int i=0;i<8;i++){
      int c = cg*8+i;
      float y = (v[i]-mu)*rstd*lng[c] + lnb[c];
      xma_s[r][c] = f2r(fmaxf(y,0.f));
    }
  }
  __syncthreads();
  // ---- stage3: q = xma @ Wq -> global
  {
    f32x4 acc[2] = {};
    for (int k0=0;k0<256;k0+=32){
      bf16x8 af = *(const bf16x8*)&xma_s[lr][k0+qd*8];
      #pragma unroll
      for (int i=0;i<2;i++){
        bf16x8 bf = *(const bf16x8*)(WqT + (long long)((w*2+i)*16+lr)*256 + k0 + qd*8);
        acc[i] = MFMA16(af,bf,acc[i]);
      }
    }
    #pragma unroll
    for (int i=0;i<2;i++)
      #pragma unroll
      for (int r=0;r<4;r++)
        qb[(long long)(row0+qd*4+r)*DIM_ + (w*2+i)*16+lr] = f2r(acc[i][r]);
  }
  // ---- stage4: kv = xn @ Wkv -> global (+ vt transposed for V cols)
  {
    const u16* Ap = xnb + (long long)(row0+lr)*DIM_;
    f32x4 acc[4] = {};
    for (int k0=0;k0<256;k0+=32){
      bf16x8 af = *(const bf16x8*)(Ap + k0 + qd*8);
      #pragma unroll
      for (int i=0;i<4;i++){
        bf16x8 bf = *(const bf16x8*)(WkvT + (long long)((w*4+i)*16+lr)*256 + k0 + qd*8);
        acc[i] = MFMA16(af,bf,acc[i]);
      }
    }
    #pragma unroll
    for (int i=0;i<4;i++){
      int col = (w*4+i)*16+lr;
      #pragma unroll
      for (int r=0;r<4;r++){
        int row = row0+qd*4+r;
        float v = acc[i][r];
        kvb[(long long)row*512 + col] = f2r(v);
        if (col >= 256)
          vt[(long long)batch*262144 + (long long)(col-256)*1024 + (row&1023)] = f2r(v);
      }
    }
  }
}

// ================= flash attention (unchanged from R6, verified) =================
__global__ __launch_bounds__(256) void flash_attn(
    const u16* __restrict__ qb, const u16* __restrict__ kvb,
    const u16* __restrict__ vt, const u16* __restrict__ bsum,
    u16* __restrict__ out)
{
  int z = blockIdx.z;          // b*4 + h
  int b = z>>2, h = z&3;
  int qt = blockIdx.x;
  int tid = threadIdx.x;
  int w = tid>>6, lane = tid&63;
  int lr = lane&15, qd = lane>>4;
  __shared__ u16 Pl[4][16][72];
  __shared__ u16 sb[4][16][72];

  int qrow0 = qt*64 + w*16;
  const u16* qp = qb + ((long long)(b*N_) + qrow0 + lr)*DIM_ + h*DH_;
  bf16x8 aq0 = *(const bf16x8*)(qp + qd*8);
  bf16x8 aq1 = *(const bf16x8*)(qp + 32 + qd*8);

  f32x4 oacc[4] = {};
  float m_r[4] = {-3e38f,-3e38f,-3e38f,-3e38f};
  float l_r[4] = {0.f,0.f,0.f,0.f};

  const u16* kbase = kvb + ((long long)(b*N_))*512 + h*DH_;
  const u16* vbase = vt + (long long)b*(DIM_*N_) + (long long)(h*DH_)*N_;
  const u16* bias_base = bsum + ((long long)z*N_ + qrow0)*(long long)N_;
  int srr = lane>>2, scc = (lane&3)*16;

  for (int jt=0; jt<16; jt++){
    int j0 = jt*64;
    {
      const u16* gs = bias_base + (long long)srr*N_ + j0 + scc;
      uint4 t0 = *(const uint4*)gs;
      uint4 t1 = *(const uint4*)(gs+8);
      *(uint4*)&sb[w][srr][scc]   = t0;
      *(uint4*)&sb[w][srr][scc+8] = t1;
    }
    f32x4 sacc[4] = {};
    #pragma unroll
    for (int nt=0; nt<4; nt++){
      const u16* kp = kbase + (long long)(j0 + nt*16 + lr)*512;
      bf16x8 bk0 = *(const bf16x8*)(kp + qd*8);
      bf16x8 bk1 = *(const bf16x8*)(kp + 32 + qd*8);
      sacc[nt] = MFMA16(aq0, bk0, sacc[nt]);
      sacc[nt] = MFMA16(aq1, bk1, sacc[nt]);
    }
    #pragma unroll
    for (int r=0;r<4;r++){
      float pv[4];
      float vmax = -3e38f;
      #pragma unroll
      for (int nt=0;nt<4;nt++){
        float v = sacc[nt][r]*0.0625f + r2f(sb[w][qd*4+r][nt*16+lr]);
        pv[nt] = v;
        vmax = fmaxf(vmax, v);
      }
      vmax = fmaxf(vmax, __shfl_xor(vmax,1));
      vmax = fmaxf(vmax, __shfl_xor(vmax,2));
      vmax = fmaxf(vmax, __shfl_xor(vmax,4));
      vmax = fmaxf(vmax, __shfl_xor(vmax,8));
      float newm = fmaxf(m_r[r], vmax);
      float alpha = __expf(m_r[r]-newm);
      m_r[r] = newm;
      float psum = 0.f;
      #pragma unroll
      for (int nt=0;nt<4;nt++){
        float p = __expf(pv[nt]-newm);
        psum += p;
        Pl[w][qd*4+r][nt*16+lr] = f2r(p);
      }
      psum += __shfl_xor(psum,1);
      psum += __shfl_xor(psum,2);
      psum += __shfl_xor(psum,4);
      psum += __shfl_xor(psum,8);
      l_r[r] = l_r[r]*alpha + psum;
      #pragma unroll
      for (int ot=0;ot<4;ot++) oacc[ot][r] *= alpha;
    }
    #pragma unroll
    for (int ks=0;ks<2;ks++){
      bf16x8 ap = *(const bf16x8*)&Pl[w][lr][ks*32 + qd*8];
      #pragma unroll
      for (int ot=0;ot<4;ot++){
        const u16* vp = vbase + (long long)(ot*16+lr)*N_ + j0 + ks*32 + qd*8;
        bf16x8 bv = *(const bf16x8*)vp;
        oacc[ot] = MFMA16(ap, bv, oacc[ot]);
      }
    }
  }
  #pragma unroll
  for (int r=0;r<4;r++){
    float inv = 1.0f/l_r[r];
    #pragma unroll
    for (int ot=0;ot<4;ot++){
      out[((long long)(b*N_) + qrow0 + qd*4 + r)*DIM_ + h*DH_ + ot*16 + lr]
          = f2r(oacc[ot][r]*inv);
    }
  }
}

// ================= layer_post: Wo+res -> LN2 -> W1+gelu -> W2+res -> x', LN1', xT =================
// grid 256 blocks x 512 thr. Block owns 16 rows. x' (post-attn) lives only in LDS.
__global__ __launch_bounds__(512) void layer_post(
    const u16* __restrict__ aob, const float* __restrict__ resx,
    const u16* __restrict__ WoT, const float* __restrict__ bo,
    const float* __restrict__ ln2g, const float* __restrict__ ln2b,
    const u16* __restrict__ W1T, const float* __restrict__ b1,
    const u16* __restrict__ W2T, const float* __restrict__ b2,
    float* __restrict__ xf_out,
    const float* __restrict__ ln1g_next, const float* __restrict__ ln1b_next,
    u16* __restrict__ xn_out, u16* __restrict__ xT_out)
{
  __shared__ float v_s[16][264];
  __shared__ u16  xn2_s[16][264];
  __shared__ u16  h1_s[16][1048];
  __shared__ float xnew_s[16][264];
  int tid = threadIdx.x;
  int w = tid>>6, lane = tid&63, lr = lane&15, qd = lane>>4;
  int row0 = blockIdx.x*16;
  int batch = row0>>10;

  // ---- stage1: x' = ao@Wo + bo + resx  -> v_s (LDS only)
  {
    const u16* Ap = aob + (long long)(row0+lr)*DIM_;
    f32x4 acc[2] = {};
    for (int k0=0;k0<256;k0+=32){
      bf16x8 af = *(const bf16x8*)(Ap + k0 + qd*8);
      #pragma unroll
      for (int i=0;i<2;i++){
        bf16x8 bf = *(const bf16x8*)(WoT + (long long)((w*2+i)*16+lr)*256 + k0 + qd*8);
        acc[i] = MFMA16(af,bf,acc[i]);
      }
    }
    #pragma unroll
    for (int i=0;i<2;i++){
      int col = (w*2+i)*16+lr;
      #pragma unroll
      for (int r=0;r<4;r++)
        v_s[qd*4+r][col] = acc[i][r] + bo[col] + resx[(long long)(row0+qd*4+r)*DIM_ + col];
    }
  }
  __syncthreads();
  // ---- LN2 -> xn2_s
  {
    int r = tid>>5, cg = tid&31;
    float v[8]; float s=0.f;
    #pragma unroll
    for (int i=0;i<8;i++){ v[i] = v_s[r][cg*8+i]; s += v[i]; }
    s += __shfl_xor(s,1); s += __shfl_xor(s,2); s += __shfl_xor(s,4); s += __shfl_xor(s,8); s += __shfl_xor(s,16);
    float mu = s*(1.0f/256.0f);
    float s2=0.f;
    #pragma unroll
    for (int i=0;i<8;i++){ float d=v[i]-mu; s2 += d*d; }
    s2 += __shfl_xor(s2,1); s2 += __shfl_xor(s2,2); s2 += __shfl_xor(s2,4); s2 += __shfl_xor(s2,8); s2 += __shfl_xor(s2,16);
    float rstd = rsqrtf(s2*(1.0f/256.0f)+1e-5f);
    #pragma unroll
    for (int i=0;i<8;i++){
      int c = cg*8+i;
      xn2_s[r][c] = f2r((v[i]-mu)*rstd*ln2g[c] + ln2b[c]);
    }
  }
  __syncthreads();
  // ---- stage2: h1 = gelu(xn2 @ W1 + b1) -> h1_s
  {
    f32x4 acc[8] = {};
    for (int k0=0;k0<256;k0+=32){
      bf16x8 af = *(const bf16x8*)&xn2_s[lr][k0+qd*8];
      #pragma unroll
      for (int i=0;i<8;i++){
        bf16x8 bf = *(const bf16x8*)(W1T + (long long)((w*8+i)*16+lr)*256 + k0 + qd*8);
        acc[i] = MFMA16(af,bf,acc[i]);
      }
    }
    #pragma unroll
    for (int i=0;i<8;i++){
      int col = (w*8+i)*16+lr;
      #pragma unroll
      for (int r=0;r<4;r++)
        h1_s[qd*4+r][col] = f2r(gelu_exact(acc[i][r] + b1[col]));
    }
  }
  __syncthreads();
  // ---- stage3: x_new = h1 @ W2 + b2 + x' -> xf_out (+ xnew_s for LN1')
  {
    f32x4 acc[2] = {};
    for (int k0=0;k0<1024;k0+=32){
      bf16x8 af = *(const bf16x8*)&h1_s[lr][k0+qd*8];
      #pragma unroll
      for (int i=0;i<2;i++){
        bf16x8 bf = *(const bf16x8*)(W2T + (long long)((w*2+i)*16+lr)*1024 + k0 + qd*8);
        acc[i] = MFMA16(af,bf,acc[i]);
      }
    }
    #pragma unroll
    for (int i=0;i<2;i++){
      int col = (w*2+i)*16+lr;
      #pragma unroll
      for (int r=0;r<4;r++){
        float v = acc[i][r] + b2[col] + v_s[qd*4+r][col];
        xf_out[(long long)(row0+qd*4+r)*DIM_ + col] = v;
        xnew_s[qd*4+r][col] = v;
      }
    }
  }
  if (ln1g_next){
    __syncthreads();
    int r = tid>>5, cg = tid&31;
    float v[8]; float s=0.f;
    #pragma unroll
    for (int i=0;i<8;i++){ v[i] = xnew_s[r][cg*8+i]; s += v[i]; }
    s += __shfl_xor(s,1); s += __shfl_xor(s,2); s += __shfl_xor(s,4); s += __shfl_xor(s,8); s += __shfl_xor(s,16);
    float mu = s*(1.0f/256.0f);
    float s2=0.f;
    #pragma unroll
    for (int i=0;i<8;i++){ float d=v[i]-mu; s2 += d*d; }
    s2 += __shfl_xor(s2,1); s2 += __shfl_xor(s2,2); s2 += __shfl_xor(s2,4); s2 += __shfl_xor(s2,8); s2 += __shfl_xor(s2,16);
    float rstd = rsqrtf(s2*(1.0f/256.0f)+1e-5f);
    int grow = row0 + r;
    #pragma unroll
    for (int i=0;i<8;i++){
      int c = cg*8+i;
      xn_out[(long long)grow*DIM_ + c] = f2r((v[i]-mu)*rstd*ln1g_next[c] + ln1b_next[c]);
      xT_out[(long long)batch*262144 + (long long)c*1024 + (grow&1023)] = f2r(v[i]);
    }
  }
}

// ---------------- host launch ----------------
extern "C" void kernel_launch(void* const* d_in, const int* in_sizes, int n_in,
                              void* d_out, int out_size, void* d_ws, size_t ws_size,
                              hipStream_t stream){
  const float* x_in   = (const float*)d_in[0];
  const float* abias  = (const float*)d_in[1];
  const float* ln1_g  = (const float*)d_in[2];
  const float* ln1_b  = (const float*)d_in[3];
  const float* Wkv    = (const float*)d_in[4];
  const float* Wq     = (const float*)d_in[5];
  const float* Wo     = (const float*)d_in[6];
  const float* bo     = (const float*)d_in[7];
  const float* ln2_g  = (const float*)d_in[8];
  const float* ln2_b  = (const float*)d_in[9];
  const float* W1     = (const float*)d_in[10];
  const float* b1     = (const float*)d_in[11];
  const float* W2     = (const float*)d_in[12];
  const float* b2     = (const float*)d_in[13];
  const float* Wg     = (const float*)d_in[14];
  const float* lng_g  = (const float*)d_in[15];
  const float* lng_b  = (const float*)d_in[16];

  char* ws = (char*)d_ws;
  float* xf   = (float*)(ws);                               // 4 MB fp32 residual
  u16*  Gb    = (u16*)(ws + (4ll<<20));                     // 8 MB
  u16*  bsum  = (u16*)(ws + (12ll<<20));                    // 32 MB
  u16*  kvb   = (u16*)(ws + (44ll<<20));                    // 4 MB
  u16*  vt    = (u16*)(ws + (48ll<<20));                    // 2 MB
  u16*  xT    = (u16*)(ws + (50ll<<20));                    // 2 MB
  u16*  xnb   = (u16*)(ws + (52ll<<20));                    // 2 MB
  u16*  qb    = (u16*)(ws + (54ll<<20));                    // 2 MB
  u16*  aob   = (u16*)(ws + (56ll<<20));                    // 2 MB
  u16*  WkvT  = (u16*)(ws + (58ll<<20));                    // 1 MB
  u16*  WqT   = (u16*)(ws + (59ll<<20));                    // 0.5 MB
  u16*  WoT   = (u16*)(ws + (59ll<<20) + (512ll<<10));      // 0.5 MB
  u16*  W1T   = (u16*)(ws + (60ll<<20));                    // 2 MB
  u16*  W2T   = (u16*)(ws + (62ll<<20));                    // 2 MB
  u16*  WgT   = (u16*)(ws + (64ll<<20));                    // 0.125 MB

  dim3 b256(256), b512(512);

  prep_bias<<<dim3(B_*N_), b256, 0, stream>>>(abias, Gb, bsum);
  tcast_all<<<dim3(32,32,25), dim3(32,8), 0, stream>>>(Wkv,Wq,Wo,W1,W2,Wg,x_in,
                                                       WkvT,WqT,WoT,W1T,W2T,WgT,xT);
  ln_kernel<<<dim3(B_*N_), b256, 0, stream>>>(x_in, xnb, ln1_g, ln1_b);

  for (int l=0; l<DEPTH_; l++){
    const float* resx = (l==0) ? x_in : xf;
    layer_pre<<<dim3(256), b512, 0, stream>>>(Gb, xT, xnb,
        WgT, WqT + (long long)l*65536, WkvT + (long long)l*131072,
        lng_g, lng_b, qb, kvb, vt);
    flash_attn<<<dim3(16,1,B_*HEADS_), b256, 0, stream>>>(qb, kvb, vt, bsum, aob);
    if (l < DEPTH_-1){
      layer_post<<<dim3(256), b512, 0, stream>>>(aob, resx,
          WoT + (long long)l*65536, bo + l*DIM_, ln2_g + l*DIM_, ln2_b + l*DIM_,
          W1T + (long long)l*262144, b1 + l*MLP_, W2T + (long long)l*262144, b2 + l*DIM_,
          xf, ln1_g + (l+1)*DIM_, ln1_b + (l+1)*DIM_, xnb, xT);
    } else {
      layer_post<<<dim3(256), b512, 0, stream>>>(aob, resx,
          WoT + (long long)l*65536, bo + l*DIM_, ln2_g + l*DIM_, ln2_b + l*DIM_,
          W1T + (long long)l*262144, b1 + l*MLP_, W2T + (long long)l*262144, b2 + l*DIM_,
          (float*)d_out, nullptr, nullptr, nullptr, nullptr);
    }
  }
}